// Round 3
// baseline (92.999 us; speedup 1.0000x reference)
//
#include <hip/hip_runtime.h>
#include <hip/hip_bf16.h>

// SubjectSpecificProjection: per-subject 2-layer MLP (256->512->512) + L2 normalize.
// R2: union Xs/Hs LDS buffer (layer1 result carried in regs across a barrier)
//     -> 71 KB LDS -> 2 blocks/CU co-resident (two independent barrier domains
//     per CU fill each other's latency stalls); __launch_bounds__(1024,8).

#define BATCH 16384
#define EEG 256
#define CLIP 512
#define NSUB 13
#define ROWS 64

// meta layout (ints):
#define M_BCNT 0        // [64][13]
#define M_BOFF 832      // [64][13]
#define M_SOFF 1664     // [14]
#define M_COFF 1678     // [14]
#define M_TOT  1692     // [13]
#define M_IDX  1720     // [16384]

typedef unsigned short u16;
typedef __attribute__((ext_vector_type(8))) short short8;
typedef __attribute__((ext_vector_type(4))) float f32x4;

__device__ __forceinline__ u16 f2bf(float f) {
    union { float f; unsigned int u; } v; v.f = f;
    unsigned int u = v.u;
    unsigned int r = (u + 0x7FFFu + ((u >> 16) & 1u)) >> 16;   // RNE
    return (u16)r;
}

// ---- weight convert + transpose: W[s][k][n] fp32 -> Wt[s][n][k] bf16 ----
__global__ __launch_bounds__(256) void convert_transpose(
    const float* __restrict__ W1, const float* __restrict__ W2,
    u16* __restrict__ w1t, u16* __restrict__ w2t) {
    __shared__ u16 T[64][72];
    int b = blockIdx.x;
    const float* src; u16* dst; int K, N;
    int s, k0, n0;
    if (b < 416) {               // W1: 13 x (256/64)x(512/64)=32 tiles
        s = b >> 5; int t = b & 31;
        k0 = (t >> 3) << 6; n0 = (t & 7) << 6;
        K = EEG; N = CLIP;
        src = W1 + (size_t)s * EEG * CLIP;
        dst = w1t + (size_t)s * CLIP * EEG;
    } else {                     // W2: 13 x 64 tiles
        b -= 416; s = b >> 6; int t = b & 63;
        k0 = (t >> 3) << 6; n0 = (t & 7) << 6;
        K = CLIP; N = CLIP;
        src = W2 + (size_t)s * CLIP * CLIP;
        dst = w2t + (size_t)s * CLIP * CLIP;
    }
    int tid = threadIdx.x;
    int rk = tid >> 2;
    int cg = (tid & 3) << 4;
    const float4* p4 = reinterpret_cast<const float4*>(src + (size_t)(k0 + rk) * N + n0 + cg);
    #pragma unroll
    for (int jj = 0; jj < 4; ++jj) {
        float4 v = p4[jj];
        T[cg + jj * 4 + 0][rk] = f2bf(v.x);
        T[cg + jj * 4 + 1][rk] = f2bf(v.y);
        T[cg + jj * 4 + 2][rk] = f2bf(v.z);
        T[cg + jj * 4 + 3][rk] = f2bf(v.w);
    }
    __syncthreads();
    u16* q = dst + (size_t)(n0 + rk) * K + k0 + cg;
    const short8* tp = reinterpret_cast<const short8*>(&T[rk][cg]);
    reinterpret_cast<short8*>(q)[0] = tp[0];
    reinterpret_cast<short8*>(q)[1] = tp[1];
}

// ---- counting-sort bucketing ----
__global__ __launch_bounds__(256) void hist_k(const int* __restrict__ sid, int* __restrict__ meta) {
    __shared__ int h[NSUB];
    int tid = threadIdx.x;
    if (tid < NSUB) h[tid] = 0;
    __syncthreads();
    int i = blockIdx.x * 256 + tid;
    atomicAdd(&h[sid[i]], 1);
    __syncthreads();
    if (tid < NSUB) meta[M_BCNT + blockIdx.x * NSUB + tid] = h[tid];
}

__global__ __launch_bounds__(256) void scan_k(int* __restrict__ meta) {
    __shared__ int lb[64][NSUB];
    __shared__ int tot[NSUB], so[14], co[14];
    int tid = threadIdx.x;
    for (int idx = tid; idx < 64 * NSUB; idx += 256)
        lb[idx / NSUB][idx % NSUB] = meta[M_BCNT + idx];
    __syncthreads();
    if (tid < NSUB) {
        int run = 0;
        for (int b = 0; b < 64; ++b) { int c = lb[b][tid]; lb[b][tid] = run; run += c; }
        tot[tid] = run;
    }
    __syncthreads();
    if (tid == 0) {
        int off = 0, c = 0;
        for (int s = 0; s < NSUB; ++s) {
            so[s] = off; co[s] = c;
            off += tot[s]; c += (tot[s] + ROWS - 1) / ROWS;
        }
        so[NSUB] = off; co[NSUB] = c;
    }
    __syncthreads();
    for (int idx = tid; idx < 64 * NSUB; idx += 256)
        meta[M_BOFF + idx] = so[idx % NSUB] + lb[idx / NSUB][idx % NSUB];
    if (tid < 14) { meta[M_SOFF + tid] = so[tid]; meta[M_COFF + tid] = co[tid]; }
    if (tid < NSUB) meta[M_TOT + tid] = tot[tid];
}

__global__ __launch_bounds__(256) void scatter2_k(const int* __restrict__ sid, int* __restrict__ meta) {
    __shared__ int h[NSUB];
    int tid = threadIdx.x;
    if (tid < NSUB) h[tid] = 0;
    __syncthreads();
    int i = blockIdx.x * 256 + tid;
    int s = sid[i];
    int r = atomicAdd(&h[s], 1);
    meta[M_IDX + meta[M_BOFF + blockIdx.x * NSUB + s] + r] = i;
}

// ---- fused MLP ----
__global__ __launch_bounds__(1024, 8) void mlp_k(
    const float* __restrict__ X, const float* __restrict__ b1,
    const float* __restrict__ b2, const u16* __restrict__ w1t,
    const u16* __restrict__ w2t, const int* __restrict__ meta,
    float* __restrict__ out) {

    __shared__ u16 buf[64 * 520];      // 65 KB union: Xs (stride 264) then Hs (stride 520)
    __shared__ float partial[64 * 16]; // 4 KB
    __shared__ float scalev[64];
    __shared__ int info[4];
    __shared__ int rowidx[64];
    __shared__ int cobuf[14], sobuf[14], totbuf[NSUB];

    int tid = threadIdx.x;

    // bijective XCD swizzle (m204)
    int nwg = gridDim.x;
    int q = nwg >> 3, r = nwg & 7;
    int xcd = blockIdx.x & 7, idx = blockIdx.x >> 3;
    int bid = (xcd < r) ? xcd * (q + 1) + idx : r * (q + 1) + (xcd - r) * q + idx;

    if (tid < 14) { cobuf[tid] = meta[M_COFF + tid]; sobuf[tid] = meta[M_SOFF + tid]; }
    if (tid < NSUB) totbuf[tid] = meta[M_TOT + tid];
    __syncthreads();
    if (tid == 0) {
        int total = cobuf[NSUB];
        if (bid < total) {
            int s = 0;
            while (s < NSUB && !(bid >= cobuf[s] && bid < cobuf[s + 1])) s++;
            int chunk = bid - cobuf[s];
            info[0] = s;
            info[1] = sobuf[s] + chunk * ROWS;
            info[2] = min(ROWS, totbuf[s] - chunk * ROWS);
        } else info[0] = -1;
    }
    __syncthreads();
    if (info[0] < 0) return;
    int s = info[0], rowbase = info[1], nrows = info[2];

    if (tid < 64) rowidx[tid] = meta[M_IDX + rowbase + min(tid, nrows - 1)];
    __syncthreads();

    // stage X tile (gather rows, fp32 -> bf16), stride 264
    {
        int row = tid >> 4, l16 = tid & 15;
        const float4* xp = reinterpret_cast<const float4*>(X + (size_t)rowidx[row] * EEG);
        u16* xd = &buf[row * 264];
        #pragma unroll
        for (int it = 0; it < 4; ++it) {
            int c4 = l16 + it * 16;
            float4 v = xp[c4];
            union { u16 u[4]; uint2 q; } pk;
            pk.u[0] = f2bf(v.x); pk.u[1] = f2bf(v.y);
            pk.u[2] = f2bf(v.z); pk.u[3] = f2bf(v.w);
            *reinterpret_cast<uint2*>(&xd[c4 * 4]) = pk.q;
        }
    }
    __syncthreads();

    int wave = tid >> 6;         // 0..15
    int lane = tid & 63;
    int c = lane & 15;
    int gl = lane >> 4;
    int wn0 = wave * 32;

    // ---- layer 1: H = relu(X @ W1 + b1), result kept in regs (packed bf16) ----
    f32x4 acc[4][2];
    #pragma unroll
    for (int mi = 0; mi < 4; ++mi)
        #pragma unroll
        for (int ni = 0; ni < 2; ++ni)
            acc[mi][ni] = (f32x4){0.f, 0.f, 0.f, 0.f};

    const u16* w1s = w1t + (size_t)s * CLIP * EEG;
    #pragma unroll 4
    for (int k0 = 0; k0 < EEG; k0 += 32) {
        short8 a[4], bb[2];
        #pragma unroll
        for (int ni = 0; ni < 2; ++ni)
            bb[ni] = *reinterpret_cast<const short8*>(&w1s[(size_t)(wn0 + ni * 16 + c) * EEG + k0 + gl * 8]);
        #pragma unroll
        for (int mi = 0; mi < 4; ++mi)
            a[mi] = *reinterpret_cast<const short8*>(&buf[(mi * 16 + c) * 264 + k0 + gl * 8]);
        #pragma unroll
        for (int mi = 0; mi < 4; ++mi)
            #pragma unroll
            for (int ni = 0; ni < 2; ++ni)
                acc[mi][ni] = __builtin_amdgcn_mfma_f32_16x16x32_bf16(a[mi], bb[ni], acc[mi][ni], 0, 0, 0);
    }

    unsigned int hp[4][2][2];    // packed bf16 pairs along i
    {
        float bias1[2];
        #pragma unroll
        for (int ni = 0; ni < 2; ++ni) bias1[ni] = b1[s * CLIP + wn0 + ni * 16 + c];
        #pragma unroll
        for (int mi = 0; mi < 4; ++mi)
            #pragma unroll
            for (int ni = 0; ni < 2; ++ni)
                #pragma unroll
                for (int j = 0; j < 2; ++j) {
                    float h0 = fmaxf(acc[mi][ni][2 * j]     + bias1[ni], 0.f);
                    float h1 = fmaxf(acc[mi][ni][2 * j + 1] + bias1[ni], 0.f);
                    hp[mi][ni][j] = (unsigned int)f2bf(h0) | ((unsigned int)f2bf(h1) << 16);
                }
    }
    __syncthreads();   // all waves done reading Xs region of buf

    // write H into buf with stride 520
    #pragma unroll
    for (int mi = 0; mi < 4; ++mi)
        #pragma unroll
        for (int ni = 0; ni < 2; ++ni)
            #pragma unroll
            for (int j = 0; j < 2; ++j) {
                int row = mi * 16 + gl * 4 + 2 * j;
                int col = wn0 + ni * 16 + c;
                buf[row * 520 + col]       = (u16)(hp[mi][ni][j] & 0xFFFF);
                buf[(row + 1) * 520 + col] = (u16)(hp[mi][ni][j] >> 16);
            }
    __syncthreads();

    // ---- layer 2: Y = H @ W2 + b2 ----
    f32x4 acc2[4][2];
    #pragma unroll
    for (int mi = 0; mi < 4; ++mi)
        #pragma unroll
        for (int ni = 0; ni < 2; ++ni)
            acc2[mi][ni] = (f32x4){0.f, 0.f, 0.f, 0.f};

    const u16* w2s = w2t + (size_t)s * CLIP * CLIP;
    #pragma unroll 4
    for (int k0 = 0; k0 < CLIP; k0 += 32) {
        short8 a[4], bb[2];
        #pragma unroll
        for (int ni = 0; ni < 2; ++ni)
            bb[ni] = *reinterpret_cast<const short8*>(&w2s[(size_t)(wn0 + ni * 16 + c) * CLIP + k0 + gl * 8]);
        #pragma unroll
        for (int mi = 0; mi < 4; ++mi)
            a[mi] = *reinterpret_cast<const short8*>(&buf[(mi * 16 + c) * 520 + k0 + gl * 8]);
        #pragma unroll
        for (int mi = 0; mi < 4; ++mi)
            #pragma unroll
            for (int ni = 0; ni < 2; ++ni)
                acc2[mi][ni] = __builtin_amdgcn_mfma_f32_16x16x32_bf16(a[mi], bb[ni], acc2[mi][ni], 0, 0, 0);
    }

    // bias + squared row-sums (this wave's 32 cols)
    float sq[4][4];
    {
        float bias2[2];
        #pragma unroll
        for (int ni = 0; ni < 2; ++ni) bias2[ni] = b2[s * CLIP + wn0 + ni * 16 + c];
        #pragma unroll
        for (int mi = 0; mi < 4; ++mi)
            #pragma unroll
            for (int i = 0; i < 4; ++i) sq[mi][i] = 0.f;
        #pragma unroll
        for (int mi = 0; mi < 4; ++mi)
            #pragma unroll
            for (int ni = 0; ni < 2; ++ni)
                #pragma unroll
                for (int i = 0; i < 4; ++i) {
                    float v = acc2[mi][ni][i] + bias2[ni];
                    acc2[mi][ni][i] = v;
                    sq[mi][i] += v * v;
                }
    }
    #pragma unroll
    for (int m = 1; m < 16; m <<= 1)
        #pragma unroll
        for (int mi = 0; mi < 4; ++mi)
            #pragma unroll
            for (int i = 0; i < 4; ++i)
                sq[mi][i] += __shfl_xor(sq[mi][i], m);

    if (c == 0) {
        #pragma unroll
        for (int mi = 0; mi < 4; ++mi)
            #pragma unroll
            for (int i = 0; i < 4; ++i)
                partial[(mi * 16 + gl * 4 + i) * 16 + wave] = sq[mi][i];
    }
    __syncthreads();
    if (tid < 64) {
        float t = 0.f;
        #pragma unroll
        for (int w = 0; w < 16; ++w) t += partial[tid * 16 + w];
        scalev[tid] = 1.f / fmaxf(sqrtf(t), 1e-12f);
    }
    __syncthreads();

    #pragma unroll
    for (int mi = 0; mi < 4; ++mi)
        #pragma unroll
        for (int i = 0; i < 4; ++i) {
            int row = mi * 16 + gl * 4 + i;
            if (row < nrows) {
                float sc = scalev[row];
                float* op = out + (size_t)rowidx[row] * CLIP + wn0 + c;
                #pragma unroll
                for (int ni = 0; ni < 2; ++ni)
                    op[ni * 16] = acc2[mi][ni][i] * sc;
            }
        }
}

extern "C" void kernel_launch(void* const* d_in, const int* in_sizes, int n_in,
                              void* d_out, int out_size, void* d_ws, size_t ws_size,
                              hipStream_t stream) {
    const float* eeg = (const float*)d_in[0];
    const int* sid   = (const int*)d_in[1];
    const float* W1  = (const float*)d_in[2];
    const float* b1  = (const float*)d_in[3];
    const float* W2  = (const float*)d_in[4];
    const float* b2  = (const float*)d_in[5];
    float* out = (float*)d_out;

    u16* w1t = (u16*)d_ws;
    u16* w2t = w1t + (size_t)NSUB * CLIP * EEG;
    int* meta = (int*)(w2t + (size_t)NSUB * CLIP * CLIP);

    convert_transpose<<<1248, 256, 0, stream>>>(W1, W2, w1t, w2t);
    hist_k<<<BATCH / 256, 256, 0, stream>>>(sid, meta);
    scan_k<<<1, 256, 0, stream>>>(meta);
    scatter2_k<<<BATCH / 256, 256, 0, stream>>>(sid, meta);
    mlp_k<<<BATCH / ROWS + NSUB, 1024, 0, stream>>>(eeg, b1, b2, w1t, w2t, meta, out);
}

// Round 4
// 87.662 us; speedup vs baseline: 1.0609x; 1.0609x over previous
//
#include <hip/hip_runtime.h>
#include <hip/hip_bf16.h>

// SubjectSpecificProjection: per-subject 2-layer MLP (256->512->512) + L2 normalize.
// R3: 512-thread blocks (8 waves, wave owns 64 cols, acc[4][4]); X staged in 64-wide
//     K-chunks (9 KB) disjoint from Hs (66.6 KB) -> LDS ~78.5 KB -> 2 blocks/CU,
//     two independent barrier domains, full 269-block co-residency.
//     __launch_bounds__(512,4) caps VGPR at 128 (R3 lesson: 8/SIMD => 64-reg cap => spill).

#define BATCH 16384
#define EEG 256
#define CLIP 512
#define NSUB 13
#define ROWS 64

// meta layout (ints):
#define M_BCNT 0        // [64][13]
#define M_BOFF 832      // [64][13]
#define M_SOFF 1664     // [14]
#define M_COFF 1678     // [14]
#define M_TOT  1692     // [13]
#define M_IDX  1720     // [16384]

typedef unsigned short u16;
typedef __attribute__((ext_vector_type(8))) short short8;
typedef __attribute__((ext_vector_type(4))) float f32x4;

__device__ __forceinline__ u16 f2bf(float f) {
    union { float f; unsigned int u; } v; v.f = f;
    unsigned int u = v.u;
    unsigned int r = (u + 0x7FFFu + ((u >> 16) & 1u)) >> 16;   // RNE
    return (u16)r;
}

// ---- weight convert + transpose: W[s][k][n] fp32 -> Wt[s][n][k] bf16 ----
__global__ __launch_bounds__(256) void convert_transpose(
    const float* __restrict__ W1, const float* __restrict__ W2,
    u16* __restrict__ w1t, u16* __restrict__ w2t) {
    __shared__ u16 T[64][72];
    int b = blockIdx.x;
    const float* src; u16* dst; int K, N;
    int s, k0, n0;
    if (b < 416) {               // W1: 13 x (256/64)x(512/64)=32 tiles
        s = b >> 5; int t = b & 31;
        k0 = (t >> 3) << 6; n0 = (t & 7) << 6;
        K = EEG; N = CLIP;
        src = W1 + (size_t)s * EEG * CLIP;
        dst = w1t + (size_t)s * CLIP * EEG;
    } else {                     // W2: 13 x 64 tiles
        b -= 416; s = b >> 6; int t = b & 63;
        k0 = (t >> 3) << 6; n0 = (t & 7) << 6;
        K = CLIP; N = CLIP;
        src = W2 + (size_t)s * CLIP * CLIP;
        dst = w2t + (size_t)s * CLIP * CLIP;
    }
    int tid = threadIdx.x;
    int rk = tid >> 2;
    int cg = (tid & 3) << 4;
    const float4* p4 = reinterpret_cast<const float4*>(src + (size_t)(k0 + rk) * N + n0 + cg);
    #pragma unroll
    for (int jj = 0; jj < 4; ++jj) {
        float4 v = p4[jj];
        T[cg + jj * 4 + 0][rk] = f2bf(v.x);
        T[cg + jj * 4 + 1][rk] = f2bf(v.y);
        T[cg + jj * 4 + 2][rk] = f2bf(v.z);
        T[cg + jj * 4 + 3][rk] = f2bf(v.w);
    }
    __syncthreads();
    u16* q = dst + (size_t)(n0 + rk) * K + k0 + cg;
    const short8* tp = reinterpret_cast<const short8*>(&T[rk][cg]);
    reinterpret_cast<short8*>(q)[0] = tp[0];
    reinterpret_cast<short8*>(q)[1] = tp[1];
}

// ---- counting-sort bucketing ----
__global__ __launch_bounds__(256) void hist_k(const int* __restrict__ sid, int* __restrict__ meta) {
    __shared__ int h[NSUB];
    int tid = threadIdx.x;
    if (tid < NSUB) h[tid] = 0;
    __syncthreads();
    int i = blockIdx.x * 256 + tid;
    atomicAdd(&h[sid[i]], 1);
    __syncthreads();
    if (tid < NSUB) meta[M_BCNT + blockIdx.x * NSUB + tid] = h[tid];
}

__global__ __launch_bounds__(256) void scan_k(int* __restrict__ meta) {
    __shared__ int lb[64][NSUB];
    __shared__ int tot[NSUB], so[14], co[14];
    int tid = threadIdx.x;
    for (int idx = tid; idx < 64 * NSUB; idx += 256)
        lb[idx / NSUB][idx % NSUB] = meta[M_BCNT + idx];
    __syncthreads();
    if (tid < NSUB) {
        int run = 0;
        for (int b = 0; b < 64; ++b) { int c = lb[b][tid]; lb[b][tid] = run; run += c; }
        tot[tid] = run;
    }
    __syncthreads();
    if (tid == 0) {
        int off = 0, c = 0;
        for (int s = 0; s < NSUB; ++s) {
            so[s] = off; co[s] = c;
            off += tot[s]; c += (tot[s] + ROWS - 1) / ROWS;
        }
        so[NSUB] = off; co[NSUB] = c;
    }
    __syncthreads();
    for (int idx = tid; idx < 64 * NSUB; idx += 256)
        meta[M_BOFF + idx] = so[idx % NSUB] + lb[idx / NSUB][idx % NSUB];
    if (tid < 14) { meta[M_SOFF + tid] = so[tid]; meta[M_COFF + tid] = co[tid]; }
    if (tid < NSUB) meta[M_TOT + tid] = tot[tid];
}

__global__ __launch_bounds__(256) void scatter2_k(const int* __restrict__ sid, int* __restrict__ meta) {
    __shared__ int h[NSUB];
    int tid = threadIdx.x;
    if (tid < NSUB) h[tid] = 0;
    __syncthreads();
    int i = blockIdx.x * 256 + tid;
    int s = sid[i];
    int r = atomicAdd(&h[s], 1);
    meta[M_IDX + meta[M_BOFF + blockIdx.x * NSUB + s] + r] = i;
}

// ---- fused MLP ----
__global__ __launch_bounds__(512, 4) void mlp_k(
    const float* __restrict__ X, const float* __restrict__ b1,
    const float* __restrict__ b2, const u16* __restrict__ w1t,
    const u16* __restrict__ w2t, const int* __restrict__ meta,
    float* __restrict__ out) {

    __shared__ u16 Hs[64 * 520];       // 66.6 KB
    __shared__ u16 Xc[64 * 72];        // 9.2 KB: one 64-wide K-chunk of X (bf16)
    __shared__ float partial[64 * 8];  // 2 KB
    __shared__ float scalev[64];
    __shared__ int info[4];
    __shared__ int rowidx[64];
    __shared__ int cobuf[14], sobuf[14], totbuf[NSUB];

    int tid = threadIdx.x;

    // bijective XCD swizzle (m204)
    int nwg = gridDim.x;
    int q = nwg >> 3, r = nwg & 7;
    int xcd = blockIdx.x & 7, idx = blockIdx.x >> 3;
    int bid = (xcd < r) ? xcd * (q + 1) + idx : r * (q + 1) + (xcd - r) * q + idx;

    if (tid < 14) { cobuf[tid] = meta[M_COFF + tid]; sobuf[tid] = meta[M_SOFF + tid]; }
    if (tid < NSUB) totbuf[tid] = meta[M_TOT + tid];
    __syncthreads();
    if (tid == 0) {
        int total = cobuf[NSUB];
        if (bid < total) {
            int s = 0;
            while (s < NSUB && !(bid >= cobuf[s] && bid < cobuf[s + 1])) s++;
            int chunk = bid - cobuf[s];
            info[0] = s;
            info[1] = sobuf[s] + chunk * ROWS;
            info[2] = min(ROWS, totbuf[s] - chunk * ROWS);
        } else info[0] = -1;
    }
    __syncthreads();
    if (info[0] < 0) return;
    int s = info[0], rowbase = info[1], nrows = info[2];

    if (tid < 64) rowidx[tid] = meta[M_IDX + rowbase + min(tid, nrows - 1)];
    __syncthreads();

    int wave = tid >> 6;         // 0..7
    int lane = tid & 63;
    int c = lane & 15;
    int gl = lane >> 4;
    int wn0 = wave * 64;         // this wave's 64 output columns

    int srow = tid >> 3;         // staging: row 0..63
    int sl8 = tid & 7;           // staging: float4 index 0..7 (and +8)

    // ---- layer 1: H = relu(X @ W1 + b1), X staged in 64-wide K-chunks ----
    f32x4 acc[4][4];
    #pragma unroll
    for (int mi = 0; mi < 4; ++mi)
        #pragma unroll
        for (int ni = 0; ni < 4; ++ni)
            acc[mi][ni] = (f32x4){0.f, 0.f, 0.f, 0.f};

    const u16* w1s = w1t + (size_t)s * CLIP * EEG;
    for (int kc = 0; kc < 4; ++kc) {
        __syncthreads();         // previous chunk's reads complete
        {
            const float4* xp = reinterpret_cast<const float4*>(
                X + (size_t)rowidx[srow] * EEG + kc * 64);
            u16* xd = &Xc[srow * 72];
            #pragma unroll
            for (int half = 0; half < 2; ++half) {
                int j = sl8 + half * 8;
                float4 v = xp[j];
                union { u16 u[4]; uint2 q; } pk;
                pk.u[0] = f2bf(v.x); pk.u[1] = f2bf(v.y);
                pk.u[2] = f2bf(v.z); pk.u[3] = f2bf(v.w);
                *reinterpret_cast<uint2*>(&xd[j * 4]) = pk.q;
            }
        }
        __syncthreads();
        #pragma unroll
        for (int k0 = 0; k0 < 64; k0 += 32) {
            int kglob = kc * 64 + k0;
            short8 a[4], bb[4];
            #pragma unroll
            for (int ni = 0; ni < 4; ++ni)
                bb[ni] = *reinterpret_cast<const short8*>(
                    &w1s[(size_t)(wn0 + ni * 16 + c) * EEG + kglob + gl * 8]);
            #pragma unroll
            for (int mi = 0; mi < 4; ++mi)
                a[mi] = *reinterpret_cast<const short8*>(&Xc[(mi * 16 + c) * 72 + k0 + gl * 8]);
            #pragma unroll
            for (int mi = 0; mi < 4; ++mi)
                #pragma unroll
                for (int ni = 0; ni < 4; ++ni)
                    acc[mi][ni] = __builtin_amdgcn_mfma_f32_16x16x32_bf16(a[mi], bb[ni], acc[mi][ni], 0, 0, 0);
        }
    }

    // bias + relu + write H to Hs (Hs disjoint from Xc -> no barrier needed before)
    {
        float bias1[4];
        #pragma unroll
        for (int ni = 0; ni < 4; ++ni) bias1[ni] = b1[s * CLIP + wn0 + ni * 16 + c];
        #pragma unroll
        for (int mi = 0; mi < 4; ++mi)
            #pragma unroll
            for (int ni = 0; ni < 4; ++ni)
                #pragma unroll
                for (int i = 0; i < 4; ++i) {
                    float h = fmaxf(acc[mi][ni][i] + bias1[ni], 0.f);
                    Hs[(mi * 16 + gl * 4 + i) * 520 + wn0 + ni * 16 + c] = f2bf(h);
                }
    }
    __syncthreads();

    // ---- layer 2: Y = H @ W2 + b2 ----
    f32x4 acc2[4][4];
    #pragma unroll
    for (int mi = 0; mi < 4; ++mi)
        #pragma unroll
        for (int ni = 0; ni < 4; ++ni)
            acc2[mi][ni] = (f32x4){0.f, 0.f, 0.f, 0.f};

    const u16* w2s = w2t + (size_t)s * CLIP * CLIP;
    #pragma unroll 4
    for (int k0 = 0; k0 < CLIP; k0 += 32) {
        short8 a[4], bb[4];
        #pragma unroll
        for (int ni = 0; ni < 4; ++ni)
            bb[ni] = *reinterpret_cast<const short8*>(
                &w2s[(size_t)(wn0 + ni * 16 + c) * CLIP + k0 + gl * 8]);
        #pragma unroll
        for (int mi = 0; mi < 4; ++mi)
            a[mi] = *reinterpret_cast<const short8*>(&Hs[(mi * 16 + c) * 520 + k0 + gl * 8]);
        #pragma unroll
        for (int mi = 0; mi < 4; ++mi)
            #pragma unroll
            for (int ni = 0; ni < 4; ++ni)
                acc2[mi][ni] = __builtin_amdgcn_mfma_f32_16x16x32_bf16(a[mi], bb[ni], acc2[mi][ni], 0, 0, 0);
    }

    // bias + squared row-sums (this wave's 64 cols)
    float sq[4][4];
    {
        float bias2[4];
        #pragma unroll
        for (int ni = 0; ni < 4; ++ni) bias2[ni] = b2[s * CLIP + wn0 + ni * 16 + c];
        #pragma unroll
        for (int mi = 0; mi < 4; ++mi)
            #pragma unroll
            for (int i = 0; i < 4; ++i) sq[mi][i] = 0.f;
        #pragma unroll
        for (int mi = 0; mi < 4; ++mi)
            #pragma unroll
            for (int ni = 0; ni < 4; ++ni)
                #pragma unroll
                for (int i = 0; i < 4; ++i) {
                    float v = acc2[mi][ni][i] + bias2[ni];
                    acc2[mi][ni][i] = v;
                    sq[mi][i] += v * v;
                }
    }
    #pragma unroll
    for (int m = 1; m < 16; m <<= 1)
        #pragma unroll
        for (int mi = 0; mi < 4; ++mi)
            #pragma unroll
            for (int i = 0; i < 4; ++i)
                sq[mi][i] += __shfl_xor(sq[mi][i], m);

    if (c == 0) {
        #pragma unroll
        for (int mi = 0; mi < 4; ++mi)
            #pragma unroll
            for (int i = 0; i < 4; ++i)
                partial[(mi * 16 + gl * 4 + i) * 8 + wave] = sq[mi][i];
    }
    __syncthreads();
    if (tid < 64) {
        float t = 0.f;
        #pragma unroll
        for (int w = 0; w < 8; ++w) t += partial[tid * 8 + w];
        scalev[tid] = 1.f / fmaxf(sqrtf(t), 1e-12f);
    }
    __syncthreads();

    #pragma unroll
    for (int mi = 0; mi < 4; ++mi)
        #pragma unroll
        for (int i = 0; i < 4; ++i) {
            int row = mi * 16 + gl * 4 + i;
            if (row < nrows) {
                float sc = scalev[row];
                float* op = out + (size_t)rowidx[row] * CLIP + wn0 + c;
                #pragma unroll
                for (int ni = 0; ni < 4; ++ni)
                    op[ni * 16] = acc2[mi][ni][i] * sc;
            }
        }
}

extern "C" void kernel_launch(void* const* d_in, const int* in_sizes, int n_in,
                              void* d_out, int out_size, void* d_ws, size_t ws_size,
                              hipStream_t stream) {
    const float* eeg = (const float*)d_in[0];
    const int* sid   = (const int*)d_in[1];
    const float* W1  = (const float*)d_in[2];
    const float* b1  = (const float*)d_in[3];
    const float* W2  = (const float*)d_in[4];
    const float* b2  = (const float*)d_in[5];
    float* out = (float*)d_out;

    u16* w1t = (u16*)d_ws;
    u16* w2t = w1t + (size_t)NSUB * CLIP * EEG;
    int* meta = (int*)(w2t + (size_t)NSUB * CLIP * CLIP);

    convert_transpose<<<1248, 256, 0, stream>>>(W1, W2, w1t, w2t);
    hist_k<<<BATCH / 256, 256, 0, stream>>>(sid, meta);
    scan_k<<<1, 256, 0, stream>>>(meta);
    scatter2_k<<<BATCH / 256, 256, 0, stream>>>(sid, meta);
    mlp_k<<<BATCH / ROWS + NSUB, 512, 0, stream>>>(eeg, b1, b2, w1t, w2t, meta, out);
}